// Round 7
// baseline (51.885 us; speedup 1.0000x reference)
//
#include <hip/hip_runtime.h>
#include <hip/hip_bf16.h>

// Problem constants (fixed by the reference).
#define M_ROWS 8192
#define K_DIM 128
#define NBINS 64    // label bins (labels 0..19; padded pow2, masked)
#define NBANDS 64   // 128-row bands
#define NPAIR 32    // band pairings (p <-> 63-p): 65 tiles each
#define NSEG 16     // segments per pairing stream (seg0: 5 tiles, rest 4)

// C = 5*log2(e): score in log2 domain is acc*C. exp(sim - m) = exp2(acc*C - m2).
#define C_LOG2 7.213475204444817f
#define INV_C 0.1386294361119891f
#define FLUSH_THR 160.0f  // exp2(x) == +0.0f for x < -150; 160 adds margin

typedef __attribute__((ext_vector_type(8))) short bf16x8;
typedef __attribute__((ext_vector_type(16))) float f32x16;

// Workspace layout (bytes). ~2.1 MB.
#define FB16_OFF 0
#define RN2_OFF (M_ROWS * K_DIM * 2)     // 2 MB bf16 features
#define NEG_OFF (RN2_OFF + M_ROWS * 4)   // +32 KB row seeds (log2 domain)
#define BMIN_OFF (NEG_OFF + M_ROWS * 4)  // +32 KB per-row neg_sum accumulator
#define SUM_OFF (BMIN_OFF + NBANDS * 4)  // band minima (uint float-bits)
#define DONE_OFF (SUM_OFF + 2 * 4)

__device__ __forceinline__ unsigned short f2bf(float f) {
  union { float f; unsigned int u; } v;
  v.f = f;
  unsigned int r = v.u + 0x7FFFu + ((v.u >> 16) & 1u);  // RNE
  return (unsigned short)(r >> 16);
}

__device__ __forceinline__ void gload_lds16(const unsigned short* g,
                                            unsigned short* l) {
  __builtin_amdgcn_global_load_lds(
      (const __attribute__((address_space(1))) void*)g,
      (__attribute__((address_space(3))) void*)l, 16, 0, 0);
}

// f32 -> bf16 convert fused with row-norm seed rn2[i] = C * ||f_i||^2, the
// per-band minimum (uint atomicMin on float bits: rn2 > 0 so order matches;
// monotone-converging and always <= true min from ANY initial content, which
// only widens the conservative flush test -> correct regardless of poison),
// zeroing of this block's 8 rows of neg[]; block 0 zeroes sums/done.
__global__ __launch_bounds__(256) void k_convert(
    const float* __restrict__ src, unsigned short* __restrict__ dst,
    float* __restrict__ rn2, unsigned int* __restrict__ bminU,
    float* __restrict__ neg, float* __restrict__ sums,
    unsigned int* __restrict__ done) {
  __shared__ int bmin_sh;
  if (threadIdx.x == 0) bmin_sh = 0x7f800000;  // +inf bits
  if (blockIdx.x == 0) {
    if (threadIdx.x < 2) sums[threadIdx.x] = 0.f;
    if (threadIdx.x == 2) *done = 0u;
  }
  if (threadIdx.x < 8) neg[blockIdx.x * 8 + threadIdx.x] = 0.f;
  __syncthreads();
  const int wid = threadIdx.x >> 6;
  const int lane = threadIdx.x & 63;
  const int half = lane >> 5;
  const int l5 = lane & 31;
  const int row = blockIdx.x * 8 + wid * 2 + half;
  const int base = row * K_DIM + l5 * 4;
  const float4 v = *reinterpret_cast<const float4*>(&src[base]);
  ushort4 o;
  o.x = f2bf(v.x);
  o.y = f2bf(v.y);
  o.z = f2bf(v.z);
  o.w = f2bf(v.w);
  *reinterpret_cast<ushort4*>(&dst[base]) = o;
  float sq = v.x * v.x + v.y * v.y + v.z * v.z + v.w * v.w;
  sq += __shfl_xor(sq, 1);
  sq += __shfl_xor(sq, 2);
  sq += __shfl_xor(sq, 4);
  sq += __shfl_xor(sq, 8);
  sq += __shfl_xor(sq, 16);
  const float r2 = sq * C_LOG2;
  if (l5 == 0) {
    rn2[row] = r2;
    atomicMin(&bmin_sh, __float_as_int(r2));  // positive floats: int order ok
  }
  __syncthreads();
  if (threadIdx.x == 0)
    atomicMin(&bminU[blockIdx.x >> 4], (unsigned int)bmin_sh);
}

// Fused sim + masked exp-sum over the UPPER TRIANGLE of the band grid
// (2080 of 4096 tiles); each tile serves both orientations from one acc.
// Block = 4 waves, each wave = 128 rows x 32 cols (wc = wid); block tile
// 128x128. A held in registers a[4][8] (128 VGPR); one B ds_read_b128 per
// k-slice per wave (8/tile/wave — half of R6, and now conflict-free).
//
// LDS B-tile: logical (col, slot16B; slot=0..15) stored at byte
// col*256 + (slot ^ (col&15))*16 — full 4-bit XOR: within a 32-lane phase,
// lanes 16 apart share a bank (2-way = free, m136); the R6 3-bit XOR was a
// 4-way conflict (1.58x). Linear LDS dest + inverse-swizzled GLOBAL source
// (rule 21), same involution on the read.
//
// Rare path (flush test trips, i.e. diagonal tiles): immediate shfl-reduce +
// atomicAdd for both orientations — no persistent s_st registers.
__global__ __launch_bounds__(256, 2) void k_main(
    const unsigned short* __restrict__ fb16, const int* __restrict__ labels,
    const float* __restrict__ rn2, const unsigned int* __restrict__ bminU,
    float* __restrict__ neg) {
  __shared__ unsigned short lds[2][128 * 128];  // 2 x 32 KB

  const int tid = threadIdx.x;
  const int lane = tid & 63;
  const int wc = tid >> 6;  // wave = col-slice owner
  const int l15 = lane & 15;
  const int lhi = lane >> 4;
  const int l31 = lane & 31;
  const int lh32 = lane >> 5;

  const int p = (int)blockIdx.x >> 4;  // pairing
  const int s = (int)blockIdx.x & 15;  // segment
  const int qs = s * 4 + (s != 0);
  const int len = (s == 0) ? 5 : 4;

  auto decode = [&](int q, int& band_, int& ct_) {
    if (q < 64 - p) {
      band_ = p;
      ct_ = p + q;
    } else {
      band_ = 63 - p;
      ct_ = q - 1;
    }
  };

  // A fragments (32x32x16): lane holds A[l&31][(l>>5)*8 + e] per k-slice.
  bf16x8 a[4][8];
#define LOAD_A(bandv)                                                        \
  {                                                                          \
    _Pragma("unroll") for (int ri = 0; ri < 4; ++ri) {                       \
      const int row_ = (bandv) * 128 + ri * 32 + l31;                        \
      _Pragma("unroll") for (int ks = 0; ks < 8; ++ks)                       \
          a[ri][ks] = *reinterpret_cast<const bf16x8*>(                      \
              &fb16[row_ * K_DIM + ks * 16 + lh32 * 8]);                     \
    }                                                                        \
  }

  // Staging: one 128x128 B-tile = 32 gload_lds (8 per wave), 1 KB each.
  // Instr (wc, it): cols wc*32+it*4+lhi, phys slot l15; source k-offset is
  // the inverse swizzle (l15 ^ (col&15))*8 shorts.
#define STAGE(buf, ctv)                                                      \
  {                                                                          \
    _Pragma("unroll") for (int it = 0; it < 8; ++it) {                       \
      const int col_ = wc * 32 + it * 4 + lhi;                               \
      gload_lds16(                                                           \
          &fb16[((ctv) * 128 + col_) * K_DIM + ((l15 ^ (col_ & 15)) << 3)],  \
          &lds[buf][wc * 4096 + it * 512]);                                  \
    }                                                                        \
  }

  int band, ct;
  decode(qs, band, ct);
  LOAD_A(band);
  STAGE(0, ct);

  int cur = 0;
  for (int qq = 0; qq < len; ++qq) {
    const bool hasNext = (qq + 1 < len);
    int nband = band, nct = ct;
    if (hasNext) {
      decode(qs + qq + 1, nband, nct);
      STAGE(cur ^ 1, nct);
      asm volatile("s_waitcnt vmcnt(8)" ::: "memory");
    } else {
      asm volatile("s_waitcnt vmcnt(0)" ::: "memory");
    }
    __builtin_amdgcn_s_barrier();

    // Conservative per-tile flush threshold (acc domain).
    const float bm = __uint_as_float(min(bminU[band], bminU[ct]));
    const float thr = (bm - FLUSH_THR) * INV_C;

    f32x16 acc[4];
#pragma unroll
    for (int ri = 0; ri < 4; ++ri)
#pragma unroll
      for (int e = 0; e < 16; ++e) acc[ri][e] = 0.f;

    const unsigned short* bufp = &lds[cur][0];
    const int col = wc * 32 + l31;
    __builtin_amdgcn_s_setprio(1);
#pragma unroll
    for (int ks = 0; ks < 8; ++ks) {
      const int phys = (ks * 2 + lh32) ^ (col & 15);
      const bf16x8 b =
          *reinterpret_cast<const bf16x8*>(&bufp[col * 128 + phys * 8]);
#pragma unroll
      for (int ri = 0; ri < 4; ++ri)
        acc[ri] = __builtin_amdgcn_mfma_f32_32x32x16_bf16(a[ri][ks], b,
                                                          acc[ri], 0, 0, 0);
    }
    __builtin_amdgcn_s_setprio(0);
    __builtin_amdgcn_s_barrier();  // all waves done reading buf[cur]

    // Per-lane flush test (fmax trees fuse to v_max3).
    float mx = -INFINITY;
#pragma unroll
    for (int ri = 0; ri < 4; ++ri)
#pragma unroll
      for (int e = 0; e < 16; ++e) mx = fmaxf(mx, acc[ri][e]);

    if (__any(mx >= thr)) {
      // Rare path: full masked exp2, both orientations, immediate commit.
      // C/D layout: col = lane&31, row = (r&3) + 8*(r>>2) + 4*(lane>>5).
      const int colT = ct * 128 + wc * 32;
      const int clab = labels[colT + l31];
      const float cseed = rn2[colT + l31];
      const bool doCol = (ct != band);
      float scol = 0.f;
#pragma unroll
      for (int ri = 0; ri < 4; ++ri) {
#pragma unroll
        for (int p4 = 0; p4 < 4; ++p4) {
          const int rbase = band * 128 + ri * 32 + lh32 * 4 + p4 * 8;
          const float4 ms = *reinterpret_cast<const float4*>(&rn2[rbase]);
          const int4 rl = *reinterpret_cast<const int4*>(&labels[rbase]);
          const float msv[4] = {ms.x, ms.y, ms.z, ms.w};
          const int rlv[4] = {rl.x, rl.y, rl.z, rl.w};
#pragma unroll
          for (int q4 = 0; q4 < 4; ++q4) {
            const int r = p4 * 4 + q4;
            const float v = acc[ri][r] * C_LOG2;
            const bool differ = (clab != rlv[q4]);
            // Row side: sum over the 32 col-lanes of this lh32 half.
            float er = differ ? exp2f(v - msv[q4]) : 0.f;
            scol += differ ? exp2f(v - cseed) : 0.f;
            er += __shfl_xor(er, 1);
            er += __shfl_xor(er, 2);
            er += __shfl_xor(er, 4);
            er += __shfl_xor(er, 8);
            er += __shfl_xor(er, 16);
            if (l31 == 0 && er > 0.f)
              atomicAdd(&neg[rbase + q4], er);
          }
        }
      }
      if (doCol) {
        // Transposed side: combine the two lh32 halves, commit per col.
        scol += __shfl_xor(scol, 32);
        if (lh32 == 0 && scol > 0.f) atomicAdd(&neg[colT + l31], scol);
      }
    }

    if (hasNext && nband != band) LOAD_A(nband);
    band = nband;
    ct = nct;
    cur ^= 1;
  }
}

// Per-row loss -> global sums; per-block LDS label histogram (no global cnt,
// no zeroing hazard); last block finalizes the scalar.
__global__ __launch_bounds__(256) void k_merge(
    const float* __restrict__ neg, const int* __restrict__ labels,
    const float* __restrict__ ious, float* __restrict__ sums,
    unsigned int* __restrict__ done, float* __restrict__ out) {
  __shared__ int h[NBINS];
  const int t = threadIdx.x;
  if (t < NBINS) h[t] = 0;
  __syncthreads();
  for (int j = t; j < M_ROWS; j += 256) atomicAdd(&h[labels[j] & (NBINS - 1)], 1);
  __syncthreads();

  const int row = blockIdx.x * 256 + t;
  const float ns = neg[row];
  int pc = h[labels[row] & (NBINS - 1)] - 1;
  if (pc < 1) pc = 1;  // reference always has pos_cnt >= 1 here; avoid 0/0
  const float loss = ns / (float)pc;  // LAMDA = 1; loss = -log_prob
  const bool keep = ious[row] >= 0.5f;
  float lv = keep ? loss : 0.f;
  float kv = keep ? 1.f : 0.f;
#pragma unroll
  for (int off = 32; off >= 1; off >>= 1) {
    lv += __shfl_xor(lv, off);
    kv += __shfl_xor(kv, off);
  }
  __shared__ float slv[4], skv[4];
  const int lane = t & 63, wv = t >> 6;
  if (lane == 0) {
    slv[wv] = lv;
    skv[wv] = kv;
  }
  __syncthreads();
  if (t == 0) {
    atomicAdd(&sums[0], slv[0] + slv[1] + slv[2] + slv[3]);
    atomicAdd(&sums[1], skv[0] + skv[1] + skv[2] + skv[3]);
    __threadfence();
    const unsigned int old = atomicAdd(done, 1u);
    if (old == (unsigned int)(M_ROWS / 256 - 1)) {
      const float a = atomicAdd(&sums[0], 0.f);  // atomic read (L2-coherent)
      const float b = atomicAdd(&sums[1], 0.f);
      out[0] = a / fmaxf(b, 1.f);
    }
  }
}

extern "C" void kernel_launch(void* const* d_in, const int* in_sizes, int n_in,
                              void* d_out, int out_size, void* d_ws,
                              size_t ws_size, hipStream_t stream) {
  const float* feat = (const float*)d_in[0];
  const int* labels = (const int*)d_in[1];
  const float* ious = (const float*)d_in[2];
  float* out = (float*)d_out;
  char* ws = (char*)d_ws;
  unsigned short* fb16 = (unsigned short*)(ws + FB16_OFF);
  float* rn2 = (float*)(ws + RN2_OFF);
  float* neg = (float*)(ws + NEG_OFF);
  unsigned int* bminU = (unsigned int*)(ws + BMIN_OFF);
  float* sums = (float*)(ws + SUM_OFF);
  unsigned int* done = (unsigned int*)(ws + DONE_OFF);

  hipLaunchKernelGGL(k_convert, dim3(M_ROWS / 8), dim3(256), 0, stream, feat,
                     fb16, rn2, bminU, neg, sums, done);
  hipLaunchKernelGGL(k_main, dim3(NPAIR * NSEG), dim3(256), 0, stream, fb16,
                     labels, rn2, bminU, neg);
  hipLaunchKernelGGL(k_merge, dim3(M_ROWS / 256), dim3(256), 0, stream, neg,
                     labels, ious, sums, done, out);
}

// Round 8
// 51.661 us; speedup vs baseline: 1.0043x; 1.0043x over previous
//
#include <hip/hip_runtime.h>
#include <hip/hip_bf16.h>

// Problem constants (fixed by the reference).
#define M_ROWS 8192
#define K_DIM 128
#define NBINS 64    // label bins (labels 0..19; padded pow2, masked)
#define NBANDS 64   // 128-row bands
#define NPAIR 32    // band pairings (p <-> 63-p): 65 tiles each
#define NSEG 16     // segments per pairing stream (seg0: 5 tiles, rest 4)

// C = 5*log2(e): score in log2 domain is acc*C. exp(sim - m) = exp2(acc*C - m2).
#define C_LOG2 7.213475204444817f
#define INV_C 0.1386294361119891f
#define FLUSH_THR 160.0f  // exp2(x) == +0.0f for x < -150; 160 adds margin

typedef __attribute__((ext_vector_type(8))) short bf16x8;
typedef __attribute__((ext_vector_type(16))) float f32x16;

// Workspace layout (bytes). ~2.1 MB.
#define FB16_OFF 0
#define RN2_OFF (M_ROWS * K_DIM * 2)     // 2 MB bf16 features
#define NEG_OFF (RN2_OFF + M_ROWS * 4)   // +32 KB row seeds (log2 domain)
#define BMIN_OFF (NEG_OFF + M_ROWS * 4)  // +32 KB per-row neg_sum accumulator
#define SUM_OFF (BMIN_OFF + NBANDS * 4)  // band minima (uint float-bits)
#define DONE_OFF (SUM_OFF + 2 * 4)

__device__ __forceinline__ unsigned short f2bf(float f) {
  union { float f; unsigned int u; } v;
  v.f = f;
  unsigned int r = v.u + 0x7FFFu + ((v.u >> 16) & 1u);  // RNE
  return (unsigned short)(r >> 16);
}

__device__ __forceinline__ void gload_lds16(const unsigned short* g,
                                            unsigned short* l) {
  __builtin_amdgcn_global_load_lds(
      (const __attribute__((address_space(1))) void*)g,
      (__attribute__((address_space(3))) void*)l, 16, 0, 0);
}

// f32 -> bf16 convert fused with row-norm seed rn2[i] = C * ||f_i||^2, the
// per-band minimum (uint atomicMin on float bits: rn2 > 0 so int order
// matches; monotone-converging and always <= true min from ANY initial
// content -> only widens the conservative flush test -> correct regardless
// of poison), zeroing of this block's 8 rows of neg[]; block 0 zeroes
// sums/done.
__global__ __launch_bounds__(256) void k_convert(
    const float* __restrict__ src, unsigned short* __restrict__ dst,
    float* __restrict__ rn2, unsigned int* __restrict__ bminU,
    float* __restrict__ neg, float* __restrict__ sums,
    unsigned int* __restrict__ done) {
  __shared__ int bmin_sh;
  if (threadIdx.x == 0) bmin_sh = 0x7f800000;  // +inf bits
  if (blockIdx.x == 0) {
    if (threadIdx.x < 2) sums[threadIdx.x] = 0.f;
    if (threadIdx.x == 2) *done = 0u;
  }
  if (threadIdx.x < 8) neg[blockIdx.x * 8 + threadIdx.x] = 0.f;
  __syncthreads();
  const int wid = threadIdx.x >> 6;
  const int lane = threadIdx.x & 63;
  const int half = lane >> 5;
  const int l5 = lane & 31;
  const int row = blockIdx.x * 8 + wid * 2 + half;
  const int base = row * K_DIM + l5 * 4;
  const float4 v = *reinterpret_cast<const float4*>(&src[base]);
  ushort4 o;
  o.x = f2bf(v.x);
  o.y = f2bf(v.y);
  o.z = f2bf(v.z);
  o.w = f2bf(v.w);
  *reinterpret_cast<ushort4*>(&dst[base]) = o;
  float sq = v.x * v.x + v.y * v.y + v.z * v.z + v.w * v.w;
  sq += __shfl_xor(sq, 1);
  sq += __shfl_xor(sq, 2);
  sq += __shfl_xor(sq, 4);
  sq += __shfl_xor(sq, 8);
  sq += __shfl_xor(sq, 16);
  const float r2 = sq * C_LOG2;
  if (l5 == 0) {
    rn2[row] = r2;
    atomicMin(&bmin_sh, __float_as_int(r2));  // positive floats: int order ok
  }
  __syncthreads();
  if (threadIdx.x == 0)
    atomicMin(&bminU[blockIdx.x >> 4], (unsigned int)bmin_sh);
}

// Fused sim + masked exp-sum over the UPPER TRIANGLE of the band grid
// (2080 of 4096 tiles); each tile serves both orientations from one acc.
//
// Wave shape: 128 rows x 32 cols (wave wc owns cols wc*32..wc*32+31) —
// one B ds_read_b128 per k-slice feeds FOUR MFMAs (MFMA:LDS-read = 4:1 vs
// 2:1 at 64x64), cutting block LDS reads per tile 64 -> 32. The CU LDS unit
// was the bottleneck (770 cyc/tile vs 256 cyc MFMA).
//
// Codegen guards (R7 post-mortem): FULLY UNROLLED tile loop (compile-time
// lds buffer index), thrT[5] preloaded in the prologue (no loads between the
// in-loop inline-asm waitcnts), no persistent s_st (rare path commits
// immediately), tight temp scoping. ~227 VGPR worst case < 256.
//
// LDS B-tile: logical (col, slot16B) at byte col*256 + (slot^(col&15))*16;
// linear LDS dest + inverse-swizzled GLOBAL source (rule 21), same
// involution on the read.
__global__ __launch_bounds__(256, 2) void k_main(
    const unsigned short* __restrict__ fb16, const int* __restrict__ labels,
    const float* __restrict__ rn2, const unsigned int* __restrict__ bminU,
    float* __restrict__ neg) {
  __shared__ unsigned short lds[2][128 * 128];  // 2 x 32 KB

  const int tid = threadIdx.x;
  const int lane = tid & 63;
  const int wc = tid >> 6;  // wave owns a 32-col slice
  const int l15 = lane & 15;
  const int lhi = lane >> 4;
  const int l31 = lane & 31;
  const int lh32 = lane >> 5;

  const int p = (int)blockIdx.x >> 4;  // pairing
  const int s = (int)blockIdx.x & 15;  // segment
  const int qs = s * 4 + (s != 0);
  const int len = (s == 0) ? 5 : 4;

  auto decode = [&](int q, int& band_, int& ct_) {
    if (q < 64 - p) {
      band_ = p;
      ct_ = p + q;
    } else {
      band_ = 63 - p;
      ct_ = q - 1;
    }
  };

  // A fragments (32x32x16): lane holds A[l&31][(l>>5)*8 + e] per k-slice.
  // 128 rows -> a[4][8] = 128 VGPR, held in registers (the win condition).
  bf16x8 a[4][8];
#define LOAD_A(bandv)                                                        \
  {                                                                          \
    _Pragma("unroll") for (int ri = 0; ri < 4; ++ri) {                       \
      const int row_ = (bandv) * 128 + ri * 32 + l31;                        \
      _Pragma("unroll") for (int ks = 0; ks < 8; ++ks)                       \
          a[ri][ks] = *reinterpret_cast<const bf16x8*>(                      \
              &fb16[row_ * K_DIM + ks * 16 + lh32 * 8]);                     \
    }                                                                        \
  }

  // Staging: one 128x128 B-tile = 32 gload_lds (8 per wave), 1 KB each.
#define STAGE(buf, ctv)                                                      \
  {                                                                          \
    _Pragma("unroll") for (int it = 0; it < 8; ++it) {                       \
      const int col_ = wc * 32 + it * 4 + lhi;                               \
      gload_lds16(                                                           \
          &fb16[((ctv) * 128 + col_) * K_DIM + ((l15 ^ (col_ & 15)) << 3)],  \
          &lds[buf][wc * 4096 + it * 512]);                                  \
    }                                                                        \
  }

  int band, ct;
  decode(qs, band, ct);
  LOAD_A(band);

  // Per-tile flush thresholds, preloaded in the PROLOGUE (keeps all global
  // loads out of the waitcnt-fenced loop).
  float thrT[5];
#pragma unroll
  for (int qq = 0; qq < 5; ++qq) {
    if (qq < len) {
      int b_, c_;
      decode(qs + qq, b_, c_);
      thrT[qq] =
          (__uint_as_float(min(bminU[b_], bminU[c_])) - FLUSH_THR) * INV_C;
    } else {
      thrT[qq] = 0.f;
    }
  }

  STAGE(0, ct);

  int cur = 0;
#pragma unroll 5
  for (int qq = 0; qq < 5; ++qq) {
    if (qq >= len) break;
    const bool hasNext = (qq + 1 < len);
    int nband = band, nct = ct;
    if (hasNext) {
      decode(qs + qq + 1, nband, nct);
      STAGE(cur ^ 1, nct);
      asm volatile("s_waitcnt vmcnt(8)" ::: "memory");
    } else {
      asm volatile("s_waitcnt vmcnt(0)" ::: "memory");
    }
    __builtin_amdgcn_s_barrier();

    f32x16 acc[4];
#pragma unroll
    for (int ri = 0; ri < 4; ++ri)
#pragma unroll
      for (int e = 0; e < 16; ++e) acc[ri][e] = 0.f;

    const unsigned short* bufp = &lds[cur][0];
    const int col = wc * 32 + l31;
    __builtin_amdgcn_s_setprio(1);
#pragma unroll
    for (int ks = 0; ks < 8; ++ks) {
      const int phys = (ks * 2 + lh32) ^ (col & 15);
      const bf16x8 b =
          *reinterpret_cast<const bf16x8*>(&bufp[col * 128 + phys * 8]);
#pragma unroll
      for (int ri = 0; ri < 4; ++ri)
        acc[ri] = __builtin_amdgcn_mfma_f32_32x32x16_bf16(a[ri][ks], b,
                                                          acc[ri], 0, 0, 0);
    }
    __builtin_amdgcn_s_setprio(0);
    __builtin_amdgcn_s_barrier();  // all waves done reading buf[cur]

    // Per-lane flush test (fmax trees fuse to v_max3; no cross-lane traffic).
    float mx = -INFINITY;
#pragma unroll
    for (int ri = 0; ri < 4; ++ri)
#pragma unroll
      for (int e = 0; e < 16; ++e) mx = fmaxf(mx, acc[ri][e]);

    if (__any(mx >= thrT[qq])) {
      // Rare path (diagonal tiles): full masked exp2, both orientations,
      // immediate shfl-reduce + atomic commit (no persistent accumulators).
      // C/D layout: col = lane&31, row = (r&3) + 8*(r>>2) + 4*(lane>>5).
      const int colT = ct * 128 + wc * 32;
      const int clab = labels[colT + l31];
      const float cseed = rn2[colT + l31];
      const bool doCol = (ct != band);
      float scol = 0.f;
#pragma unroll
      for (int ri = 0; ri < 4; ++ri) {
#pragma unroll
        for (int p4 = 0; p4 < 4; ++p4) {
          const int rbase = band * 128 + ri * 32 + lh32 * 4 + p4 * 8;
          const float4 ms = *reinterpret_cast<const float4*>(&rn2[rbase]);
          const int4 rl = *reinterpret_cast<const int4*>(&labels[rbase]);
          const float msv[4] = {ms.x, ms.y, ms.z, ms.w};
          const int rlv[4] = {rl.x, rl.y, rl.z, rl.w};
#pragma unroll
          for (int q4 = 0; q4 < 4; ++q4) {
            const int r = p4 * 4 + q4;
            const float v = acc[ri][r] * C_LOG2;
            const bool differ = (clab != rlv[q4]);
            float er = differ ? exp2f(v - msv[q4]) : 0.f;
            scol += differ ? exp2f(v - cseed) : 0.f;
            // Row side: reduce over the 32 col-lanes of this lh32 half
            // (xor bits 0-4 stay within the half).
            er += __shfl_xor(er, 1);
            er += __shfl_xor(er, 2);
            er += __shfl_xor(er, 4);
            er += __shfl_xor(er, 8);
            er += __shfl_xor(er, 16);
            if (l31 == 0 && er > 0.f) atomicAdd(&neg[rbase + q4], er);
          }
        }
      }
      if (doCol) {
        // Transposed side: combine lh32 halves (each holds 32 of the 64
        // rows... here 64 of the 128 rows per half), commit per col.
        scol += __shfl_xor(scol, 32);
        if (lh32 == 0 && scol > 0.f) atomicAdd(&neg[colT + l31], scol);
      }
    }

    if (hasNext && nband != band) LOAD_A(nband);
    band = nband;
    ct = nct;
    cur ^= 1;
  }
}

// Per-row loss -> global sums; per-block LDS label histogram (no global cnt,
// no zeroing hazard); last block finalizes the scalar.
__global__ __launch_bounds__(256) void k_merge(
    const float* __restrict__ neg, const int* __restrict__ labels,
    const float* __restrict__ ious, float* __restrict__ sums,
    unsigned int* __restrict__ done, float* __restrict__ out) {
  __shared__ int h[NBINS];
  const int t = threadIdx.x;
  if (t < NBINS) h[t] = 0;
  __syncthreads();
  for (int j = t; j < M_ROWS; j += 256)
    atomicAdd(&h[labels[j] & (NBINS - 1)], 1);
  __syncthreads();

  const int row = blockIdx.x * 256 + t;
  const float ns = neg[row];
  int pc = h[labels[row] & (NBINS - 1)] - 1;
  if (pc < 1) pc = 1;  // reference always has pos_cnt >= 1 here; avoid 0/0
  const float loss = ns / (float)pc;  // LAMDA = 1; loss = -log_prob
  const bool keep = ious[row] >= 0.5f;
  float lv = keep ? loss : 0.f;
  float kv = keep ? 1.f : 0.f;
#pragma unroll
  for (int off = 32; off >= 1; off >>= 1) {
    lv += __shfl_xor(lv, off);
    kv += __shfl_xor(kv, off);
  }
  __shared__ float slv[4], skv[4];
  const int lane = t & 63, wv = t >> 6;
  if (lane == 0) {
    slv[wv] = lv;
    skv[wv] = kv;
  }
  __syncthreads();
  if (t == 0) {
    atomicAdd(&sums[0], slv[0] + slv[1] + slv[2] + slv[3]);
    atomicAdd(&sums[1], skv[0] + skv[1] + skv[2] + skv[3]);
    __threadfence();
    const unsigned int old = atomicAdd(done, 1u);
    if (old == (unsigned int)(M_ROWS / 256 - 1)) {
      const float a = atomicAdd(&sums[0], 0.f);  // atomic read (L2-coherent)
      const float b = atomicAdd(&sums[1], 0.f);
      out[0] = a / fmaxf(b, 1.f);
    }
  }
}

extern "C" void kernel_launch(void* const* d_in, const int* in_sizes, int n_in,
                              void* d_out, int out_size, void* d_ws,
                              size_t ws_size, hipStream_t stream) {
  const float* feat = (const float*)d_in[0];
  const int* labels = (const int*)d_in[1];
  const float* ious = (const float*)d_in[2];
  float* out = (float*)d_out;
  char* ws = (char*)d_ws;
  unsigned short* fb16 = (unsigned short*)(ws + FB16_OFF);
  float* rn2 = (float*)(ws + RN2_OFF);
  float* neg = (float*)(ws + NEG_OFF);
  unsigned int* bminU = (unsigned int*)(ws + BMIN_OFF);
  float* sums = (float*)(ws + SUM_OFF);
  unsigned int* done = (unsigned int*)(ws + DONE_OFF);

  hipLaunchKernelGGL(k_convert, dim3(M_ROWS / 8), dim3(256), 0, stream, feat,
                     fb16, rn2, bminU, neg, sums, done);
  hipLaunchKernelGGL(k_main, dim3(NPAIR * NSEG), dim3(256), 0, stream, fb16,
                     labels, rn2, bminU, neg);
  hipLaunchKernelGGL(k_merge, dim3(M_ROWS / 256), dim3(256), 0, stream, neg,
                     labels, ious, sums, done, out);
}